// Round 12
// baseline (129.413 us; speedup 1.0000x reference)
//
#include <hip/hip_runtime.h>
#include <stdint.h>
#include <stddef.h>

// ---------------------------------------------------------------------------
// cseft reassociated, W1 folded into U. 5 launches, repacked (R12):
//   1. prep_y: yb=bf16(y), w23t=bf16([W2|W3]^T)     (critical-path only)
//   2. stage_kv: kvt[2048,4096] = w23t @ yb^T
//   3. build_u + conv: blocks 0..127 Ut GEMM (uses 128 of 512 co-resident
//      slots); blocks 128..447 convert x->xb, W1->w1b on the idle CUs
//      (xb/w1b not needed until launches 4/5 -> safe, and overlapped)
//   4. build_m:  M[2048,512] = Ut @ w1b  (K=1024, bf16)
//   5. gemm_out: out[4096,2048] = xb @ M^T  (K=512, fp32)
// N=4096 K=512 H=8 Dh=128 nItem=256 nSet=16 hardcoded.
//
// gemm_tile (R6/R11-verified, 129.1us): BK=64 (128B cache-line staging),
// dbuf 2x32KB, 1 barrier/step, T2 both-sides XOR swizzle (linear LDS dest +
// pre-swizzled global source + XOR'd ds_read), T1 bijective XCD swizzle.
//
// SESSION LEDGER (measured, do not reopen):
// - R10 T14 reg-staged f32 operands: 156.2 (-27). gload_lds + pre-cvt wins.
// - Fusion arc: R3 coop no-op under graph capture; R5 sw-barrier replay-
//   diverged (stale per-XCD L2); R8 acquire-per-poll 530us; R9 wbl2/inv
//   211us (L2 wipe -> full refetch). Kernel boundaries win.
// - R7 qb-dataflow 132.2; R4 depth-2 vmcnt null; R1 split 147.5.
// Accounting: ~85-90us harness fill floor + ~10us gaps + prep + GEMMs
// (staging-BW-bound: 32KB/CU/step ~ 1170cy at L2 aggregate BW).
// ---------------------------------------------------------------------------

typedef short short8 __attribute__((ext_vector_type(8)));
typedef float f32x4 __attribute__((ext_vector_type(4)));

#define AS1 __attribute__((address_space(1)))
#define AS3 __attribute__((address_space(3)))

__device__ __forceinline__ void gl_lds16(const void* g, void* l) {
    __builtin_amdgcn_global_load_lds((AS1 void*)(uintptr_t)g, (AS3 void*)l, 16, 0, 0);
}

__device__ __forceinline__ short f2bf(float f) {
    union { float f; unsigned u; } v; v.f = f;
    unsigned r = v.u + 0x7FFFu + ((v.u >> 16) & 1u);
    return (short)(r >> 16);
}

// --- cvt8: one unit = 8 fp32 -> 8 bf16 (32B read, 16B write) ---------------
__device__ __forceinline__ void cvt8(const float* __restrict__ in,
                                     short* __restrict__ o, int i) {
    const float4* p = (const float4*)in + (size_t)i * 2;
    float4 a = p[0], c4 = p[1];
    short8 s8;
    s8[0] = f2bf(a.x);  s8[1] = f2bf(a.y);
    s8[2] = f2bf(a.z);  s8[3] = f2bf(a.w);
    s8[4] = f2bf(c4.x); s8[5] = f2bf(c4.y);
    s8[6] = f2bf(c4.z); s8[7] = f2bf(c4.w);
    *((short8*)o + i) = s8;
}

// --- prep_y: 0..1023 y->yb; 1024..2047 W2/W3 -> w23t (T). 2048 blocks. -----
__global__ __launch_bounds__(256)
void prep_y(const float* __restrict__ y, const float* __restrict__ W2,
            const float* __restrict__ W3, short* __restrict__ yb,
            short* __restrict__ w23t) {
    const int b = blockIdx.x, tid = threadIdx.x;
    if (b < 1024) {
        cvt8(y, yb, b * 256 + tid);
        return;
    }
    __shared__ float t[32][33];
    const int b2 = b - 1024;                     // 0..1023
    const int z = b2 >> 9;                       // 0: W2, 1: W3
    const float* W = z ? W3 : W2;
    short* Wt = w23t + (size_t)z * 1024 * 512;
    const int b3 = b2 & 511;
    const int bx = (b3 & 31) * 32, by = (b3 >> 5) * 32;
    const int tx = tid & 31, ty = tid >> 5;
    #pragma unroll
    for (int j = 0; j < 4; ++j)
        t[ty + j * 8][tx] = W[(size_t)(by + ty + j * 8) * 1024 + bx + tx];
    __syncthreads();
    #pragma unroll
    for (int j = 0; j < 4; ++j)
        Wt[(size_t)(bx + ty + j * 8) * 512 + by + tx] = f2bf(t[tx][ty + j * 8]);
}

// --- generic MFMA tile: C[128x128] = A[.,K] * Bt[.,K]^T --------------------
// 4 waves 2x2; OUTMODE: 0 = f32 store, 1 = bf16 store, 2 = bf16*scale.
// BK=64, dbuf 2x32KB, 1 __syncthreads per step, XOR-swizzled LDS (T2).
template <int OUTMODE>
__device__ __forceinline__
void gemm_tile(const short* __restrict__ A, int lda,
               const short* __restrict__ Bt, int ldb,
               void* __restrict__ Cout, int ldc, int K,
               int bx, int by, float scale, char* smem) {
    const int tid = threadIdx.x;
    const int wave = tid >> 6, lane = tid & 63;
    const int quad = lane >> 4, ml = lane & 15;
    const int m0 = by * 128, n0 = bx * 128;
    const int wm0 = (wave >> 1) * 64, wn0 = (wave & 1) * 64;
    const int rl = lane >> 3;            // row within an 8-row group (0..7)
    const int ch = lane & 7;             // 16B chunk within 128B row (0..7)
    const int sch = ch ^ rl;             // source-swizzled chunk (involution)

    f32x4 acc[4][4];
    #pragma unroll
    for (int i = 0; i < 4; ++i)
        #pragma unroll
        for (int j = 0; j < 4; ++j) {
            acc[i][j][0] = 0.f; acc[i][j][1] = 0.f;
            acc[i][j][2] = 0.f; acc[i][j][3] = 0.f;
        }

    auto STAGE = [&](char* sbuf, int kt) {
        #pragma unroll
        for (int j = 0; j < 4; ++j) {
            const int r = (wave * 4 + j) * 8 + rl;
            gl_lds16(A + (size_t)(m0 + r) * lda + kt + sch * 8,
                     sbuf + (wave * 4 + j) * 1024 + lane * 16);
        }
        #pragma unroll
        for (int j = 0; j < 4; ++j) {
            const int r = (wave * 4 + j) * 8 + rl;
            gl_lds16(Bt + (size_t)(n0 + r) * ldb + kt + sch * 8,
                     sbuf + 16384 + (wave * 4 + j) * 1024 + lane * 16);
        }
    };

    const int nt = K >> 6;               // >= 4 at every call site
    STAGE(smem, 0);
    __syncthreads();                     // drain vmcnt(0): buf0 ready

    for (int t = 0; t < nt; ++t) {
        char* sbuf = smem + (t & 1) * 32768;
        if (t + 1 < nt)
            STAGE(smem + ((t + 1) & 1) * 32768, (t + 1) * 64);  // prefetch

        const short* sA = (const short*)sbuf;
        const short* sB = (const short*)(sbuf + 16384);
        #pragma unroll
        for (int kk = 0; kk < 2; ++kk) {
            short8 af[4], bfr[4];
            #pragma unroll
            for (int mt = 0; mt < 4; ++mt) {
                const int row = wm0 + mt * 16 + ml;
                af[mt] = *(const short8*)(sA + row * 64 +
                                          (((kk << 2) + quad) ^ (row & 7)) * 8);
            }
            #pragma unroll
            for (int nt2 = 0; nt2 < 4; ++nt2) {
                const int row = wn0 + nt2 * 16 + ml;
                bfr[nt2] = *(const short8*)(sB + row * 64 +
                                            (((kk << 2) + quad) ^ (row & 7)) * 8);
            }
            #pragma unroll
            for (int mt = 0; mt < 4; ++mt)
                #pragma unroll
                for (int nt2 = 0; nt2 < 4; ++nt2)
                    acc[mt][nt2] = __builtin_amdgcn_mfma_f32_16x16x32_bf16(
                        af[mt], bfr[nt2], acc[mt][nt2], 0, 0, 0);
        }
        __syncthreads();  // next buf ready; all waves done reading sbuf
    }

    // C/D layout: col = lane&15, row = quad*4 + reg
    #pragma unroll
    for (int mt = 0; mt < 4; ++mt)
        #pragma unroll
        for (int nt2 = 0; nt2 < 4; ++nt2) {
            const int col = n0 + wn0 + nt2 * 16 + ml;
            #pragma unroll
            for (int r = 0; r < 4; ++r) {
                const int row = m0 + wm0 + mt * 16 + quad * 4 + r;
                float v = acc[mt][nt2][r];
                if (OUTMODE == 2) v *= scale;
                if (OUTMODE == 0)
                    ((float*)Cout)[(size_t)row * ldc + col] = v;
                else
                    ((short*)Cout)[(size_t)row * ldc + col] = f2bf(v);
            }
        }
}

// stage_kv: kvt[2048,4096] = w23t @ yb^T. 512 blocks, XCD-swizzled.
__global__ __launch_bounds__(256)
void stage_kv(const short* __restrict__ yb, const short* __restrict__ w23t,
              short* __restrict__ kvt) {
    __shared__ char smem[65536];
    const int b = (blockIdx.x & 7) * 64 + (blockIdx.x >> 3);   // T1 bijective
    gemm_tile<1>(w23t, 512, yb, 512, kvt, 4096, 512,
                 b & 31, b >> 5, 1.f, smem);
}

// build_u + conversions: 448 blocks (all co-resident at 2/CU).
//   0..127:   Ut tile (s,h) = scale * V_s @ K_s^T (K=256), XCD-swizzled
//   128..383: x -> xb   (256 blocks x 4 units x 256 thr)
//   384..447: W1 -> w1b (64 blocks x 4 units x 256 thr)
// xb/w1b are consumed only by launches 4/5 -> kernel boundary covers them.
__global__ __launch_bounds__(256)
void build_u_conv(const short* __restrict__ kvt, const float* __restrict__ cw,
                  short* __restrict__ Ut, const float* __restrict__ x,
                  const float* __restrict__ W1, short* __restrict__ xb,
                  short* __restrict__ w1b) {
    __shared__ char smem[65536];
    const int bid = blockIdx.x, tid = threadIdx.x;
    if (bid < 128) {
        const int b = (bid & 7) * 16 + (bid >> 3);             // 128 % 8 == 0
        const int s = b & 15, h = b >> 4;
        const float scale = cw[h] * (0.08838834764831845f / 256.0f);
        gemm_tile<2>(kvt + (size_t)(1024 + h * 128) * 4096 + s * 256, 4096, // V
                     kvt + (size_t)(h * 128) * 4096 + s * 256, 4096,        // K
                     Ut + (size_t)(s * 128) * 1024 + h * 128, 1024, 256,
                     0, 0, scale, smem);
        return;
    }
    if (bid < 384) {
        const int u = bid - 128;                 // 0..255; x: 256k units
        #pragma unroll
        for (int it = 0; it < 4; ++it)
            cvt8(x, xb, u * 1024 + it * 256 + tid);
        return;
    }
    {
        const int u = bid - 384;                 // 0..63; W1: 64k units
        #pragma unroll
        for (int it = 0; it < 4; ++it)
            cvt8(W1, w1b, u * 1024 + it * 256 + tid);
    }
}

// build_m: M[2048,512] = Ut @ W1 (Bt = w1b row-major [512,1024]), K=1024.
// grid (4,16) = 64 blocks.
__global__ __launch_bounds__(256)
void build_m(const short* __restrict__ Ut, const short* __restrict__ w1b,
             short* __restrict__ M) {
    __shared__ char smem[65536];
    gemm_tile<1>(Ut, 1024, w1b, 1024, M, 512, 1024,
                 blockIdx.x, blockIdx.y, 1.f, smem);
}

// out[4096,2048] = xb @ M^T, fp32, K=512. 512 blocks (XCD-swizzled).
__global__ __launch_bounds__(256)
void gemm_out(const short* __restrict__ xb, const short* __restrict__ M,
              float* __restrict__ out) {
    __shared__ char smem[65536];
    const int b = (blockIdx.x & 7) * 64 + (blockIdx.x >> 3);
    gemm_tile<0>(xb, 512, M, 512, out, 2048, 512,
                 b & 15, b >> 4, 1.f, smem);
}

extern "C" void kernel_launch(void* const* d_in, const int* in_sizes, int n_in,
                              void* d_out, int out_size, void* d_ws, size_t ws_size,
                              hipStream_t stream) {
    const float* x  = (const float*)d_in[0];  // [4096, 512]
    const float* y  = (const float*)d_in[1];  // [4096, 512]
    const float* W1 = (const float*)d_in[2];  // [512, 1024]
    const float* W2 = (const float*)d_in[3];
    const float* W3 = (const float*)d_in[4];
    const float* cw = (const float*)d_in[5];  // [8]
    float* out = (float*)d_out;               // [4096, 16, 128]

    short* xb   = (short*)d_ws;                       // 4096*512
    short* yb   = xb   + (size_t)4096 * 512;          // 4096*512
    short* w23t = yb   + (size_t)4096 * 512;          // 2048*512 (transposed)
    short* w1b  = w23t + (size_t)2048 * 512;          // 512*1024 (row-major)
    short* kvt  = w1b  + (size_t)512 * 1024;          // 2048*4096
    short* Ut   = kvt  + (size_t)2048 * 4096;         // 2048*1024
    short* M    = Ut   + (size_t)2048 * 1024;         // 2048*512

    prep_y<<<2048, 256, 0, stream>>>(y, W2, W3, yb, w23t);
    stage_kv<<<512, 256, 0, stream>>>(yb, w23t, kvt);
    build_u_conv<<<448, 256, 0, stream>>>(kvt, cw, Ut, x, W1, xb, w1b);
    build_m<<<dim3(4, 16), 256, 0, stream>>>(Ut, w1b, M);
    gemm_out<<<512, 256, 0, stream>>>(xb, M, out);
}